// Round 6
// baseline (594.585 us; speedup 1.0000x reference)
//
#include <hip/hip_runtime.h>
#include <hip/hip_bf16.h>

#define N_COARSE 12500
#define N_FINE   50000

typedef __bf16 bf16x8 __attribute__((ext_vector_type(8)));
typedef __bf16 bf16x4 __attribute__((ext_vector_type(4)));
typedef float  f32x4  __attribute__((ext_vector_type(4)));

// ---------------------------------------------------------------------------
// Fragment conventions (v_mfma_f32_16x16x32_bf16), HW-verified:
//   a-frag: lane holds A[row = lane&15][k = (lane>>4)*8 + j]
//   b-frag: lane holds B[k = (lane>>4)*8 + j][col = lane&15]
//   d     : lane holds D[row = (lane>>4)*4 + j][col = lane&15]
// ---------------------------------------------------------------------------

__device__ __forceinline__ bf16x8 cvt8(f32x4 x, f32x4 y) {
    bf16x8 r;
    r[0] = (__bf16)x[0]; r[1] = (__bf16)x[1]; r[2] = (__bf16)x[2]; r[3] = (__bf16)x[3];
    r[4] = (__bf16)y[0]; r[5] = (__bf16)y[1]; r[6] = (__bf16)y[2]; r[7] = (__bf16)y[3];
    return r;
}

// Barrier with LDS-only fence (avoids __syncthreads' vmcnt(0) drain).
__device__ __forceinline__ void lds_barrier() {
    asm volatile("s_waitcnt lgkmcnt(0)" ::: "memory");
    __builtin_amdgcn_s_barrier();
}

// ---- LDS A-tile: [64 rows][256 bf16] = 32 KB, XOR-swizzled ----------------
__device__ __forceinline__ int swz(int row, int byte) { return byte ^ ((row & 7) << 4); }

__device__ __forceinline__ void st_a(__bf16* lds, int row, int cs, bf16x8 v) {
    *(bf16x8*)((char*)lds + swz(row, row * 512 + cs * 16)) = v;
}
__device__ __forceinline__ bf16x8 ld_a(const __bf16* lds, int row, int ka) {
    return *(const bf16x8*)((const char*)lds + swz(row, row * 512 + ka * 2));
}

// stage 64 consecutive f32 rows (256 cols) -> bf16 LDS tile; coalesced loads
template<int NT>
__device__ __forceinline__ void stage_f32(const float* __restrict__ A, long row0,
                                          __bf16* lds, int tid, long maxrow) {
    const int r0 = tid >> 5, cs = tid & 31;
    constexpr int RPI = NT / 32;
    #pragma unroll
    for (int i = 0; i < 64 / RPI; ++i) {
        int row = r0 + i * RPI;
        long gr = row0 + row; if (gr > maxrow) gr = maxrow;
        const float* p = A + gr * 256 + cs * 8;
        f32x4 x = *(const f32x4*)p, y = *(const f32x4*)(p + 4);
        st_a(lds, row, cs, cvt8(x, y));
    }
}

// 64x64-per-wave MFMA over one 256-wide K segment, A from LDS, B packed global
__device__ __forceinline__ void mfma_tile(const __bf16* lds, const bf16x8* __restrict__ packB,
                                          int N, int c0, int ksb,
                                          f32x4 (&acc)[4][4], int lane) {
    const int g = lane >> 4, r15 = lane & 15;
    #pragma unroll
    for (int ks = 0; ks < 8; ++ks) {
        bf16x8 a[4];
        #pragma unroll
        for (int rt = 0; rt < 4; ++rt)
            a[rt] = ld_a(lds, rt * 16 + r15, ks * 32 + g * 8);
        const size_t kb = (size_t)((ksb + ks) * 4 + g) * N;
        #pragma unroll
        for (int ct = 0; ct < 4; ++ct) {
            bf16x8 b = packB[kb + c0 + ct * 16 + r15];
            #pragma unroll
            for (int rt = 0; rt < 4; ++rt)
                acc[rt][ct] = __builtin_amdgcn_mfma_f32_16x16x32_bf16(a[rt], b, acc[rt][ct], 0, 0, 0);
        }
    }
}

// ---------------------------------------------------------------------------
__global__ __launch_bounds__(256) void k_pack(const float* __restrict__ W,
                                              __bf16* __restrict__ dst, int K, int N) {
    int idx = blockIdx.x * 256 + threadIdx.x;
    if (idx >= K * N) return;
    int k = idx / N, n = idx % N;
    dst[((size_t)(k >> 3) * N + n) * 8 + (k & 7)] = (__bf16)W[(size_t)k * N + n];
}

__global__ __launch_bounds__(256) void k_cvt(const float* __restrict__ src,
                                             __bf16* __restrict__ dst, int n4) {
    int i = blockIdx.x * 256 + threadIdx.x;
    if (i >= n4) return;
    f32x4 v = ((const f32x4*)src)[i];
    bf16x4 o;
    o[0] = (__bf16)v[0]; o[1] = (__bf16)v[1]; o[2] = (__bf16)v[2]; o[3] = (__bf16)v[3];
    ((bf16x4*)dst)[i] = o;
}

// ---------------- counting sort of fine indices by coarse id ----------------
__global__ __launch_bounds__(256) void k_zero(int* __restrict__ cnt, int n) {
    int i = blockIdx.x * 256 + threadIdx.x;
    if (i < n) cnt[i] = 0;
}
__global__ __launch_bounds__(256) void k_hist(const int* __restrict__ up, int* __restrict__ cnt) {
    int n = blockIdx.x * 256 + threadIdx.x;
    if (n < N_FINE) atomicAdd(&cnt[up[n]], 1);
}
// single-block exclusive prefix sum over N_COARSE bins
__global__ __launch_bounds__(1024) void k_scan(const int* __restrict__ cnt,
                                               int* __restrict__ base) {
    __shared__ int buf[1024];
    __shared__ int carry;
    const int tid = threadIdx.x;
    if (tid == 0) carry = 0;
    __syncthreads();
    for (int c0 = 0; c0 < N_COARSE; c0 += 1024) {
        int i = c0 + tid;
        int v = (i < N_COARSE) ? cnt[i] : 0;
        buf[tid] = v; __syncthreads();
        #pragma unroll
        for (int off = 1; off < 1024; off <<= 1) {
            int t = (tid >= off) ? buf[tid - off] : 0;
            __syncthreads();
            buf[tid] += t;
            __syncthreads();
        }
        int total = buf[1023];
        if (i < N_COARSE) base[i] = carry + buf[tid] - v;
        __syncthreads();
        if (tid == 0) carry += total;
        __syncthreads();
    }
}
__global__ __launch_bounds__(256) void k_place(const int* __restrict__ up,
                                               int* __restrict__ cursor,
                                               int* __restrict__ perm) {
    int n = blockIdx.x * 256 + threadIdx.x;
    if (n < N_FINE) {
        int pos = atomicAdd(&cursor[up[n]], 1);
        perm[pos] = n;
    }
}

// ---------------------------------------------------------------------------
// Coarse: LE = last_equ @ W_last_equ -> LEp in MFMA D-layout (bf16).
// ---------------------------------------------------------------------------
__global__ __launch_bounds__(256) void k_coarse_equ(
    const float* __restrict__ last_equ, const bf16x8* __restrict__ packW,
    __bf16* __restrict__ LEp)
{
    __shared__ __attribute__((aligned(16))) __bf16 As[64 * 256];
    const int tid = threadIdx.x, lane = tid & 63, wid = tid >> 6;
    const long row0 = (long)blockIdx.x * 64;
    stage_f32<256>(last_equ, row0, As, tid, (long)N_COARSE * 16 - 1);
    lds_barrier();
    f32x4 acc[4][4] = {};
    mfma_tile(As, packW, 256, wid * 64, 0, acc, lane);
    #pragma unroll
    for (int rt = 0; rt < 4; ++rt) {
        int coarse = (int)(row0 >> 4) + rt;
        #pragma unroll
        for (int ct = 0; ct < 4; ++ct) {
            int cg = wid * 4 + ct;
            bf16x4 v;
            v[0] = (__bf16)acc[rt][ct][0]; v[1] = (__bf16)acc[rt][ct][1];
            v[2] = (__bf16)acc[rt][ct][2]; v[3] = (__bf16)acc[rt][ct][3];
            *(bf16x4*)(LEp + ((size_t)(coarse * 16 + cg) * 64 + lane) * 4) = v;
        }
    }
}

// ---------------------------------------------------------------------------
// Fine fused, coarse-sorted: block handles 4 fine points with (mostly) the
// SAME coarse parent -> LE gathers collapse to L1/L2 hits. Bijective XCD
// swizzle keeps neighboring sorted blocks (sharing coarse points) on the
// same XCD's L2.
// ---------------------------------------------------------------------------
__global__ __launch_bounds__(256) void k_fine_equ(
    const float* __restrict__ cur_equ, const bf16x8* __restrict__ packW,
    const __bf16* __restrict__ LEp, const int* __restrict__ up,
    const int* __restrict__ perm, __bf16* __restrict__ equ)
{
    __shared__ __attribute__((aligned(16))) __bf16 As[64 * 256];
    const int tid = threadIdx.x, lane = tid & 63, wid = tid >> 6;

    // bijective XCD-chunked swizzle (nwg = 12500 = 8*1562 + 4)
    const int q = N_FINE / 4 / 8, r = N_FINE / 4 % 8;   // 1562, 4
    int xcd = blockIdx.x & 7, idx = blockIdx.x >> 3;
    int wg = (xcd < r ? xcd * (q + 1) : r * (q + 1) + (xcd - r) * q) + idx;

    const int n0 = wg * 4;
    int pn[4], cu[4];
    #pragma unroll
    for (int rt = 0; rt < 4; ++rt) pn[rt] = perm[n0 + rt];   // uniform scalars
    #pragma unroll
    for (int rt = 0; rt < 4; ++rt) cu[rt] = up[pn[rt]];

    // stage 4 gathered 16-row chunks of cur_equ (static pn index -> no scratch)
    const int r0 = tid >> 5, cs = tid & 31;
    #pragma unroll
    for (int rt = 0; rt < 4; ++rt)
        #pragma unroll
        for (int ii = 0; ii < 2; ++ii) {
            int row = rt * 16 + ii * 8 + r0;
            const float* p = cur_equ + ((long)pn[rt] * 16 + ii * 8 + r0) * 256 + cs * 8;
            f32x4 x = *(const f32x4*)p, y = *(const f32x4*)(p + 4);
            st_a(As, row, cs, cvt8(x, y));
        }

    // LE gathers issued after staging loads (FIFO vmcnt: survive the barrier)
    __builtin_amdgcn_sched_barrier(0);
    bf16x4 le[4][4];
    #pragma unroll
    for (int rt = 0; rt < 4; ++rt)
        #pragma unroll
        for (int ct = 0; ct < 4; ++ct)
            le[rt][ct] = *(const bf16x4*)(LEp +
                ((size_t)(cu[rt] * 16 + wid * 4 + ct) * 64 + lane) * 4);

    lds_barrier();
    f32x4 acc[4][4] = {};
    mfma_tile(As, packW, 256, wid * 64, 0, acc, lane);

    #pragma unroll
    for (int rt = 0; rt < 4; ++rt) {
        #pragma unroll
        for (int ct = 0; ct < 4; ++ct) {
            float s = acc[rt][ct][0] * (float)le[rt][ct][0]
                    + acc[rt][ct][1] * (float)le[rt][ct][1]
                    + acc[rt][ct][2] * (float)le[rt][ct][2]
                    + acc[rt][ct][3] * (float)le[rt][ct][3];
            s += __shfl_xor(s, 16, 64);   // basis reduce over lane-group bit 0
            s += __shfl_xor(s, 32, 64);   // basis reduce over lane-group bit 1
            if (lane < 16)
                equ[(size_t)pn[rt] * 256 + wid * 64 + ct * 16 + lane] =
                    (__bf16)(s * 0.0625f);
        }
    }
}

// ---------------------------------------------------------------------------
// Output: out = [ last_inv[up] | cur_inv | equ ] @ W_mlp  (K=768)
// ---------------------------------------------------------------------------
__global__ __launch_bounds__(512) void k_out(
    const __bf16* __restrict__ li_bf, const float* __restrict__ cur_inv,
    const __bf16* __restrict__ equ, const bf16x8* __restrict__ packW,
    const int* __restrict__ up, float* __restrict__ out)
{
    __shared__ __attribute__((aligned(16))) __bf16 As[64 * 256];
    const int tid = threadIdx.x, lane = tid & 63, wid = tid >> 6;
    const int row0 = blockIdx.x * 64;
    const int c0 = wid * 64;
    const int r0 = tid >> 5, cs = tid & 31;
    f32x4 acc[4][4] = {};

    // seg0: gathered last_inv rows (bf16)
    #pragma unroll
    for (int i = 0; i < 4; ++i) {
        int row = r0 + i * 16;
        int gr = row0 + row; if (gr > N_FINE - 1) gr = N_FINE - 1;
        st_a(As, row, cs, *(const bf16x8*)(li_bf + (size_t)up[gr] * 256 + cs * 8));
    }
    lds_barrier();
    mfma_tile(As, packW, 512, c0, 0, acc, lane);
    lds_barrier();

    // seg1: cur_inv (f32)
    stage_f32<512>(cur_inv, row0, As, tid, N_FINE - 1);
    lds_barrier();
    mfma_tile(As, packW, 512, c0, 8, acc, lane);
    lds_barrier();

    // seg2: equ (bf16)
    #pragma unroll
    for (int i = 0; i < 4; ++i) {
        int row = r0 + i * 16;
        int gr = row0 + row; if (gr > N_FINE - 1) gr = N_FINE - 1;
        st_a(As, row, cs, *(const bf16x8*)(equ + (size_t)gr * 256 + cs * 8));
    }
    lds_barrier();
    mfma_tile(As, packW, 512, c0, 16, acc, lane);

    const int g = lane >> 4, r15 = lane & 15;
    #pragma unroll
    for (int rt = 0; rt < 4; ++rt)
        #pragma unroll
        for (int j = 0; j < 4; ++j) {
            int r = row0 + rt * 16 + g * 4 + j;
            if (r < N_FINE)
                #pragma unroll
                for (int ct = 0; ct < 4; ++ct)
                    out[(size_t)r * 512 + c0 + ct * 16 + r15] = acc[rt][ct][j];
        }
}

extern "C" void kernel_launch(void* const* d_in, const int* in_sizes, int n_in,
                              void* d_out, int out_size, void* d_ws, size_t ws_size,
                              hipStream_t stream) {
    const float* last_inv = (const float*)d_in[0];
    const float* cur_inv  = (const float*)d_in[1];
    const float* last_equ = (const float*)d_in[2];
    const float* cur_equ  = (const float*)d_in[3];
    const int*   up       = (const int*)d_in[4];
    const float* W_le     = (const float*)d_in[5];
    const float* W_ce     = (const float*)d_in[6];
    const float* W_mlp    = (const float*)d_in[7];
    float* out = (float*)d_out;

    // workspace carve-up (~136 MB)
    char* w = (char*)d_ws;
    __bf16* LEp    = (__bf16*)w;  w += (size_t)N_COARSE * 16 * 256 * 2;  // 102.4 MB
    __bf16* equ    = (__bf16*)w;  w += (size_t)N_FINE * 256 * 2;        //  25.6 MB
    __bf16* li_bf  = (__bf16*)w;  w += (size_t)N_COARSE * 256 * 2;      //   6.4 MB
    __bf16* packLE = (__bf16*)w;  w += (size_t)256 * 256 * 2;
    __bf16* packCE = (__bf16*)w;  w += (size_t)256 * 256 * 2;
    __bf16* packM  = (__bf16*)w;  w += (size_t)768 * 512 * 2;
    int* cnt    = (int*)w;  w += (size_t)N_COARSE * 4;
    int* cursor = (int*)w;  w += (size_t)N_COARSE * 4;
    int* perm   = (int*)w;  w += (size_t)N_FINE * 4;

    // ---- counting sort of fine indices by coarse parent ----
    k_zero <<<(N_COARSE + 255) / 256, 256, 0, stream>>>(cnt, N_COARSE);
    k_hist <<<(N_FINE + 255) / 256, 256, 0, stream>>>(up, cnt);
    k_scan <<<1, 1024, 0, stream>>>(cnt, cursor);
    k_place<<<(N_FINE + 255) / 256, 256, 0, stream>>>(up, cursor, perm);

    k_pack<<<256, 256, 0, stream>>>(W_le, packLE, 256, 256);
    k_pack<<<256, 256, 0, stream>>>(W_ce, packCE, 256, 256);
    k_pack<<<1536, 256, 0, stream>>>(W_mlp, packM, 768, 512);
    k_cvt<<<3125, 256, 0, stream>>>(last_inv, li_bf, N_COARSE * 256 / 4);

    k_coarse_equ<<<N_COARSE * 16 / 64, 256, 0, stream>>>(
        last_equ, (const bf16x8*)packLE, LEp);

    k_fine_equ<<<N_FINE / 4, 256, 0, stream>>>(
        cur_equ, (const bf16x8*)packCE, LEp, up, perm, equ);

    k_out<<<(N_FINE + 63) / 64, 512, 0, stream>>>(
        li_bf, cur_inv, equ, (const bf16x8*)packM, up, out);
}